// Round 5
// baseline (5613.918 us; speedup 1.0000x reference)
//
#include <hip/hip_runtime.h>
#include <hip/hip_bf16.h>

typedef __attribute__((ext_vector_type(8))) short s8;
typedef __attribute__((ext_vector_type(4))) float f4;
typedef __attribute__((ext_vector_type(4))) unsigned int u4;

#define DEVI static __device__ __forceinline__

DEVI float bf2f(short u) {
  union { float f; unsigned int i; } v;
  v.i = ((unsigned int)(unsigned short)u) << 16;
  return v.f;
}
DEVI short f2bf(float f) {
  union { float f; unsigned int i; } v; v.f = f;
  unsigned int r = v.i + 0x7fffu + ((v.i >> 16) & 1u);
  return (short)(r >> 16);
}
DEVI void gload_lds16(const void* g, void* l) {
  __builtin_amdgcn_global_load_lds(
      (const __attribute__((address_space(1))) unsigned int*)g,
      (__attribute__((address_space(3))) unsigned int*)l, 16, 0, 0);
}
DEVI float sigm(float x) { return 1.f / (1.f + __expf(-x)); }

// agent-coherent 16B load (bypass L1/L2, served by IF$)
DEVI u4 load4_agent(const unsigned int* p) {
  u4 v;
  asm volatile("global_load_dwordx4 %0, %1, off sc0 sc1"
               : "=v"(v) : "v"(p) : "memory");
  return v;
}
DEVI void vm0_fence() {
  asm volatile("s_waitcnt vmcnt(0)" ::: "memory");
  __builtin_amdgcn_sched_barrier(0);  // keep reg-ops from hoisting past the wait
}

// ---------------- converts ----------------
// x [64][512][1024] f32  ->  xbf [512][64][1024] bf16 (t-major rows)
__global__ void k_x_relayout(const float* __restrict__ in, short* __restrict__ out) {
  long idx8 = (long)blockIdx.x * blockDim.x + threadIdx.x;
  long E = idx8 * 8;
  long row = E >> 10;
  long col = E & 1023;
  long t = row >> 6, b = row & 63;
  const float* src = in + ((b << 9) + t) * 1024 + col;
  float4 a = *(const float4*)(src);
  float4 c = *(const float4*)(src + 4);
  s8 o;
  o[0] = f2bf(a.x); o[1] = f2bf(a.y); o[2] = f2bf(a.z); o[3] = f2bf(a.w);
  o[4] = f2bf(c.x); o[5] = f2bf(c.y); o[6] = f2bf(c.z); o[7] = f2bf(c.w);
  *(s8*)(out + E) = o;
}

// src [1024][1024] f32 row-major [k][n]  ->  dst [1024][1024] bf16 at [n][k]
__global__ void k_transpose_c(const float* __restrict__ src, short* __restrict__ dst) {
  __shared__ float tile[32][33];
  int n0 = blockIdx.x * 32, k0 = blockIdx.y * 32;
  int lx = threadIdx.x & 31, ly = threadIdx.x >> 5;
#pragma unroll
  for (int r = 0; r < 32; r += 8)
    tile[ly + r][lx] = src[(long)(k0 + ly + r) * 1024 + n0 + lx];
  __syncthreads();
#pragma unroll
  for (int r = 0; r < 32; r += 8)
    dst[(long)(n0 + ly + r) * 1024 + k0 + lx] = f2bf(tile[lx][ly + r]);
}

__global__ void k_bcat(const float* __restrict__ b0, const float* __restrict__ b1,
                       const float* __restrict__ b2, const float* __restrict__ b3,
                       float* __restrict__ o) {
  int i = blockIdx.x * 256 + threadIdx.x;
  int j = i & 1023;
  float v;
  switch (i >> 10) { case 0: v = b0[j]; break; case 1: v = b1[j]; break;
                     case 2: v = b2[j]; break; default: v = b3[j]; }
  o[i] = v;
}

// ---------------- bf16 GEMM: C[M][N] = A[M][K] @ Bt[N][K]^T + bias ----------------
// REMAP 0: linear. 1: row (t*64+b) -> (b*512+t). 2: XG permute [t][rb][ug][g][16r][32u].
template <typename OutT, int REMAP>
__global__ __launch_bounds__(256) void k_gemm_bt(
    const short* __restrict__ A, const short* __restrict__ Bt,
    const float* __restrict__ bias, OutT* __restrict__ C,
    int M, int N, int K) {
  __shared__ __align__(16) char As[8192];
  __shared__ __align__(16) char Bs[8192];
  const int tid = threadIdx.x;
  const int wid = tid >> 6, lane = tid & 63;
  const int lr = lane & 15, lk = lane >> 4;
  const int wy = wid >> 1, wx = wid & 1;
  const long bm = (long)blockIdx.y * 128, bn = (long)blockIdx.x * 128;
  const char* Ab = (const char*)A;
  const char* Bb = (const char*)Bt;
  f4 acc[4][4];
#pragma unroll
  for (int i = 0; i < 4; ++i)
#pragma unroll
    for (int j = 0; j < 4; ++j) acc[i][j] = f4{0.f, 0.f, 0.f, 0.f};

  for (int k0 = 0; k0 < K; k0 += 32) {
#pragma unroll
    for (int p = 0; p < 2; ++p) {
      int off = p * 4096 + tid * 16;
      int r = off >> 6, cb = off & 63;
      int sw = cb ^ ((r & 3) << 4);
      gload_lds16(Ab + ((bm + r) * K + k0) * 2 + sw, As + p * 4096 + wid * 1024);
      gload_lds16(Bb + ((bn + r) * K + k0) * 2 + sw, Bs + p * 4096 + wid * 1024);
    }
    __syncthreads();
    s8 af[4], bfr[4];
#pragma unroll
    for (int mi = 0; mi < 4; ++mi) {
      int r = wy * 64 + mi * 16 + lr;
      int x = r * 64 + lk * 16;
      af[mi] = *(const s8*)(As + (x ^ ((r & 3) << 4)));
    }
#pragma unroll
    for (int ni = 0; ni < 4; ++ni) {
      int r = wx * 64 + ni * 16 + lr;
      int x = r * 64 + lk * 16;
      bfr[ni] = *(const s8*)(Bs + (x ^ ((r & 3) << 4)));
    }
#pragma unroll
    for (int mi = 0; mi < 4; ++mi)
#pragma unroll
      for (int ni = 0; ni < 4; ++ni)
        acc[mi][ni] = __builtin_amdgcn_mfma_f32_16x16x32_bf16(af[mi], bfr[ni], acc[mi][ni], 0, 0, 0);
    __syncthreads();
  }
#pragma unroll
  for (int mi = 0; mi < 4; ++mi)
#pragma unroll
    for (int ni = 0; ni < 4; ++ni)
#pragma unroll
      for (int j = 0; j < 4; ++j) {
        long row = bm + wy * 64 + mi * 16 + lk * 4 + j;
        long col = bn + wx * 64 + ni * 16 + lr;
        float v = acc[mi][ni][j] + bias[col];
        long off;
        if constexpr (REMAP == 1) {
          off = ((row & 63) * 512 + (row >> 6)) * (long)N + col;
        } else if constexpr (REMAP == 2) {
          long tt = row >> 6, b = row & 63;
          long gg = col >> 10, u = col & 1023;
          off = ((((tt << 2) + (b >> 4)) << 5) + (u >> 5)) * 2048 +
                (gg << 9) + ((b & 15) << 5) + (u & 31);
        } else {
          off = row * (long)N + col;
        }
        if constexpr (sizeof(OutT) == 2) C[off] = f2bf(v);
        else                              C[off] = v;
      }
}

// ---------------- persistent LSTM recurrence ----------------
// 128 WGs x 512 threads. WG = (rb = wg&3: 16 batch rows) x (ug = wg>>2: 32 units).
// 8 waves = (gate g = wid&3) x (K-half kh = wid>>2); each wave: 16 rows x 32 units,
// K = 512 (its half), partials summed via the pre[] LDS exchange.
// h exchange: u32 word per unit = (bf16 h << 16) | tag(t+1). No barrier: consumers
// poll the data words (agent-scope dwordx4) until tags match. Weights in VGPRs.
__global__ __launch_bounds__(512, 2) void k_lstm_p(
    const short* __restrict__ XG,     // [512][4][32][2048] permuted, bias folded
    const short* __restrict__ Wht,    // [4096][1024]
    unsigned int* __restrict__ hbuf,  // [2][64][1024] tagged h words
    short* __restrict__ HS) {         // [512][64][1024] bf16
  __shared__ __align__(16) char hA[32768];   // [32 chunk][16 row][64B], swizzled
  __shared__ float pre[2][4 * 16 * 33];      // [kh][gate][row][unit(pad 33)]

  const int tid = threadIdx.x;
  const int wg = blockIdx.x;
  const int wid = tid >> 6, lane = tid & 63;
  const int lr = lane & 15, lk = lane >> 4;
  const int g = wid & 3, kh = wid >> 2;
  const int rb = wg & 3, ug = wg >> 2;

  // recurrent-weight B-fragments: [nt(2)][kc(16)] = 32 x s8 = 128 VGPR
  s8 wf[32];
  {
    const short* wbase = Wht + (long)(g * 1024 + ug * 32 + lr) * 1024 + kh * 512 + lk * 8;
#pragma unroll
    for (int nt = 0; nt < 2; ++nt)
#pragma unroll
      for (int kc = 0; kc < 16; ++kc)
        wf[nt * 16 + kc] = *(const s8*)(wbase + nt * 16384 + kc * 32);
  }
#pragma unroll
  for (int i = 0; i < 32; ++i) asm volatile("" : "+v"(wf[i]));

  const int r_ew = tid >> 5, u_ew = tid & 31;     // elementwise (row, unit)
  const int grow = rb * 16 + r_ew, gu = ug * 32 + u_ew;
  float c = 0.f;

  // h0 = 0, tag = 1 (parity-0 buffer); consumers poll, so no init barrier needed
  __hip_atomic_store(&hbuf[(long)grow * 1024 + gu], 1u,
                     __ATOMIC_RELAXED, __HIP_MEMORY_SCOPE_AGENT);

  // XG preload for t=0 (kh==0 waves carry xg)
  float xgv[8];
  short nx[8];
  if (kh == 0) {
    const short* xp = XG + (long)(rb * 32 + ug) * 2048 + g * 512;
#pragma unroll
    for (int nt = 0; nt < 2; ++nt)
#pragma unroll
      for (int j = 0; j < 4; ++j)
        nx[nt * 4 + j] = xp[(lk * 4 + j) * 32 + nt * 16 + lr];
  }

  const int sr = tid >> 5, sc = tid & 31;  // staging (row, col-group)

  for (int t = 0; t < 512; ++t) {
    const unsigned int* cur = hbuf + (t & 1) * 65536;
    unsigned int* nxt = hbuf + ((t + 1) & 1) * 65536;
    const unsigned int tagw = (unsigned int)(t + 1) * 0x10001u;

    // ---- poll-stage h rows [rb*16,+16): 8 x dwordx4 per thread ----
    {
      const unsigned int* rowp = cur + (long)(rb * 16 + sr) * 1024 + sc * 4;
      u4 v[8];
#pragma unroll
      for (int i = 0; i < 8; ++i) v[i] = load4_agent(rowp + i * 128);
      vm0_fence();
#pragma unroll
      for (int i = 0; i < 8; ++i) {
        unsigned int t01 = __builtin_amdgcn_perm(v[i][1], v[i][0], 0x05040100u);
        unsigned int t23 = __builtin_amdgcn_perm(v[i][3], v[i][2], 0x05040100u);
        int guard = 0;
        while ((t01 != tagw) | (t23 != tagw)) {
          v[i] = load4_agent(rowp + i * 128);
          vm0_fence();
          t01 = __builtin_amdgcn_perm(v[i][1], v[i][0], 0x05040100u);
          t23 = __builtin_amdgcn_perm(v[i][3], v[i][2], 0x05040100u);
          if (++guard > (1 << 18)) break;
        }
        unsigned int h0 = __builtin_amdgcn_perm(v[i][1], v[i][0], 0x07060302u);
        unsigned int h1 = __builtin_amdgcn_perm(v[i][3], v[i][2], 0x07060302u);
        int u0 = sc * 4 + i * 128;
        int a = ((u0 >> 5) << 10) + sr * 64 + ((u0 & 31) << 1);
        a ^= (sr & 3) << 4;
        *(unsigned long long*)(hA + a) =
            ((unsigned long long)h1 << 32) | h0;
      }
    }

    // consume xg(t); issue prefetch for t+1 (drained by next step's vm0_fence)
    if (kh == 0) {
#pragma unroll
      for (int q = 0; q < 8; ++q) xgv[q] = bf2f(nx[q]);
      int tn = (t + 1) & 511;
      const short* xp = XG + (long)((tn * 4 + rb) * 32 + ug) * 2048 + g * 512;
#pragma unroll
      for (int nt = 0; nt < 2; ++nt)
#pragma unroll
        for (int j = 0; j < 4; ++j)
          nx[nt * 4 + j] = xp[(lk * 4 + j) * 32 + nt * 16 + lr];
    }
    __syncthreads();

    // ---- MFMA: 16 A-reads, 32 MFMA per wave ----
    f4 a0{0.f, 0.f, 0.f, 0.f}, a1{0.f, 0.f, 0.f, 0.f};
#pragma unroll
    for (int kc = 0; kc < 16; ++kc) {
      int ad = ((kh * 16 + kc) << 10) + lr * 64 + lk * 16;
      ad ^= (lr & 3) << 4;
      s8 ah = *(const s8*)(hA + ad);
      a0 = __builtin_amdgcn_mfma_f32_16x16x32_bf16(ah, wf[kc], a0, 0, 0, 0);
      a1 = __builtin_amdgcn_mfma_f32_16x16x32_bf16(ah, wf[16 + kc], a1, 0, 0, 0);
    }

    // ---- gate-partial exchange (C/D: col=lr, row=lk*4+j) ----
#pragma unroll
    for (int j = 0; j < 4; ++j) {
      float e0 = a0[j], e1 = a1[j];
      if (kh == 0) { e0 += xgv[j]; e1 += xgv[4 + j]; }
      pre[kh][(g * 16 + lk * 4 + j) * 33 + lr] = e0;
      pre[kh][(g * 16 + lk * 4 + j) * 33 + 16 + lr] = e1;
    }
    __syncthreads();

    // ---- elementwise state update ----
    {
      float pi = pre[0][(0 * 16 + r_ew) * 33 + u_ew] + pre[1][(0 * 16 + r_ew) * 33 + u_ew];
      float pf = pre[0][(1 * 16 + r_ew) * 33 + u_ew] + pre[1][(1 * 16 + r_ew) * 33 + u_ew];
      float po = pre[0][(2 * 16 + r_ew) * 33 + u_ew] + pre[1][(2 * 16 + r_ew) * 33 + u_ew];
      float pc = pre[0][(3 * 16 + r_ew) * 33 + u_ew] + pre[1][(3 * 16 + r_ew) * 33 + u_ew];
      float fi = sigm(pi), ff = sigm(pf), fo = sigm(po);
      float ch = tanhf(pc);
      c = ff * c + fi * ch;
      float h = fo * tanhf(c);
      short hh = f2bf(h);
      unsigned int w = ((unsigned int)(unsigned short)hh << 16) | (unsigned int)(t + 2);
      __hip_atomic_store(&nxt[(long)grow * 1024 + gu], w,
                         __ATOMIC_RELAXED, __HIP_MEMORY_SCOPE_AGENT);
      HS[(long)t * 65536 + (long)grow * 1024 + gu] = hh;
    }
    // NOTE: no barrier — next step's tag-poll is the synchronization.
  }
}

// ---------------- launch ----------------
extern "C" void kernel_launch(void* const* d_in, const int* in_sizes, int n_in,
                              void* d_out, int out_size, void* d_ws, size_t ws_size,
                              hipStream_t stream) {
  const float* x = (const float*)d_in[0];
  const float* Wx[4] = {(const float*)d_in[1], (const float*)d_in[4], (const float*)d_in[7], (const float*)d_in[10]};
  const float* Wh[4] = {(const float*)d_in[2], (const float*)d_in[5], (const float*)d_in[8], (const float*)d_in[11]};
  const float* bg[4] = {(const float*)d_in[3], (const float*)d_in[6], (const float*)d_in[9], (const float*)d_in[12]};
  const float* Why = (const float*)d_in[13];
  const float* by  = (const float*)d_in[14];

  char* ws = (char*)d_ws;                     // layout (bytes):
  short* xbf  = (short*)(ws);                 // 67,108,864  x bf16 [512][64][1024]
  short* HS   = (short*)(ws);                 // reuses xbf (dead after big GEMM)
  short* Wxt  = (short*)(ws + 67108864);      //  8,388,608
  short* Wht  = (short*)(ws + 75497472);      //  8,388,608
  short* Whyt = (short*)(ws + 83886080);      //  2,097,152
  float* bcat = (float*)(ws + 85983232);      //     16,384
  short* XG   = (short*)(ws + 85999616);      // 268,435,456 [512][4][32][2048] permuted
  unsigned int* hbuf = (unsigned int*)(ws + 354435072);  // 524,288 [2][64][1024]

  hipLaunchKernelGGL(k_x_relayout, dim3(16384), dim3(256), 0, stream, x, xbf);
  for (int gi = 0; gi < 4; ++gi) {
    hipLaunchKernelGGL(k_transpose_c, dim3(32, 32), dim3(256), 0, stream, Wx[gi], Wxt + (long)gi * 1048576);
    hipLaunchKernelGGL(k_transpose_c, dim3(32, 32), dim3(256), 0, stream, Wh[gi], Wht + (long)gi * 1048576);
  }
  hipLaunchKernelGGL(k_transpose_c, dim3(32, 32), dim3(256), 0, stream, Why, Whyt);
  hipLaunchKernelGGL(k_bcat, dim3(16), dim3(256), 0, stream, bg[0], bg[1], bg[2], bg[3], bcat);

  hipLaunchKernelGGL((k_gemm_bt<short, 2>), dim3(32, 256), dim3(256), 0, stream,
                     xbf, Wxt, bcat, XG, 32768, 4096, 1024);

  {
    void* args[] = { (void*)&XG, (void*)&Wht, (void*)&hbuf, (void*)&HS };
    hipLaunchCooperativeKernel((void*)k_lstm_p, dim3(128), dim3(512), args, 0, stream);
  }

  hipLaunchKernelGGL((k_gemm_bt<float, 1>), dim3(8, 256), dim3(256), 0, stream,
                     HS, Whyt, by, (float*)d_out, 32768, 1024, 1024);
}

// Round 7
// 3577.079 us; speedup vs baseline: 1.5694x; 1.5694x over previous
//
#include <hip/hip_runtime.h>
#include <hip/hip_bf16.h>

typedef __attribute__((ext_vector_type(8))) short s8;
typedef __attribute__((ext_vector_type(4))) float f4;
typedef __attribute__((ext_vector_type(4))) unsigned int u4;

#define DEVI static __device__ __forceinline__

DEVI float bf2f(short u) {
  union { float f; unsigned int i; } v;
  v.i = ((unsigned int)(unsigned short)u) << 16;
  return v.f;
}
DEVI short f2bf(float f) {
  union { float f; unsigned int i; } v; v.f = f;
  unsigned int r = v.i + 0x7fffu + ((v.i >> 16) & 1u);
  return (short)(r >> 16);
}
DEVI void gload_lds16(const void* g, void* l) {
  __builtin_amdgcn_global_load_lds(
      (const __attribute__((address_space(1))) unsigned int*)g,
      (__attribute__((address_space(3))) unsigned int*)l, 16, 0, 0);
}
DEVI float sigm(float x) { return 1.f / (1.f + __expf(-x)); }

// sc0: bypass L1, serviced by local (XCD) L2 — fast path for same-XCD producer
DEVI u4 load4_sc0(const unsigned int* p) {
  u4 v;
  asm volatile("global_load_dwordx4 %0, %1, off sc0" : "=v"(v) : "v"(p) : "memory");
  return v;
}
// sc0 sc1: bypass L1+L2, serviced by IF$ — correctness fallback for any mapping
DEVI u4 load4_sc01(const unsigned int* p) {
  u4 v;
  asm volatile("global_load_dwordx4 %0, %1, off sc0 sc1" : "=v"(v) : "v"(p) : "memory");
  return v;
}
DEVI void vm0_fence() {
  asm volatile("s_waitcnt vmcnt(0)" ::: "memory");
  __builtin_amdgcn_sched_barrier(0);
}
DEVI int tagok(u4 v, unsigned int tagw) {
  unsigned int t01 = __builtin_amdgcn_perm(v[1], v[0], 0x05040100u);
  unsigned int t23 = __builtin_amdgcn_perm(v[3], v[2], 0x05040100u);
  return (t01 == tagw) & (t23 == tagw);
}

// ---------------- converts ----------------
// x [64][512][1024] f32  ->  xbf [512][64][1024] bf16 (t-major rows)
__global__ void k_x_relayout(const float* __restrict__ in, short* __restrict__ out) {
  long idx8 = (long)blockIdx.x * blockDim.x + threadIdx.x;
  long E = idx8 * 8;
  long row = E >> 10;
  long col = E & 1023;
  long t = row >> 6, b = row & 63;
  const float* src = in + ((b << 9) + t) * 1024 + col;
  float4 a = *(const float4*)(src);
  float4 c = *(const float4*)(src + 4);
  s8 o;
  o[0] = f2bf(a.x); o[1] = f2bf(a.y); o[2] = f2bf(a.z); o[3] = f2bf(a.w);
  o[4] = f2bf(c.x); o[5] = f2bf(c.y); o[6] = f2bf(c.z); o[7] = f2bf(c.w);
  *(s8*)(out + E) = o;
}

// src [1024][1024] f32 row-major [k][n]  ->  dst [1024][1024] bf16 at [n][k]
__global__ void k_transpose_c(const float* __restrict__ src, short* __restrict__ dst) {
  __shared__ float tile[32][33];
  int n0 = blockIdx.x * 32, k0 = blockIdx.y * 32;
  int lx = threadIdx.x & 31, ly = threadIdx.x >> 5;
#pragma unroll
  for (int r = 0; r < 32; r += 8)
    tile[ly + r][lx] = src[(long)(k0 + ly + r) * 1024 + n0 + lx];
  __syncthreads();
#pragma unroll
  for (int r = 0; r < 32; r += 8)
    dst[(long)(n0 + ly + r) * 1024 + k0 + lx] = f2bf(tile[lx][ly + r]);
}

__global__ void k_bcat(const float* __restrict__ b0, const float* __restrict__ b1,
                       const float* __restrict__ b2, const float* __restrict__ b3,
                       float* __restrict__ o) {
  int i = blockIdx.x * 256 + threadIdx.x;
  int j = i & 1023;
  float v;
  switch (i >> 10) { case 0: v = b0[j]; break; case 1: v = b1[j]; break;
                     case 2: v = b2[j]; break; default: v = b3[j]; }
  o[i] = v;
}

// ---------------- bf16 GEMM: C[M][N] = A[M][K] @ Bt[N][K]^T + bias ----------------
// REMAP 0: linear. 1: row (t*64+b) -> (b*512+t).
// REMAP 2: XG permute [t][rb8][ug32][g4][row8][u32] for the recurrence kernel.
template <typename OutT, int REMAP>
__global__ __launch_bounds__(256) void k_gemm_bt(
    const short* __restrict__ A, const short* __restrict__ Bt,
    const float* __restrict__ bias, OutT* __restrict__ C,
    int M, int N, int K) {
  __shared__ __align__(16) char As[8192];
  __shared__ __align__(16) char Bs[8192];
  const int tid = threadIdx.x;
  const int wid = tid >> 6, lane = tid & 63;
  const int lr = lane & 15, lk = lane >> 4;
  const int wy = wid >> 1, wx = wid & 1;
  const long bm = (long)blockIdx.y * 128, bn = (long)blockIdx.x * 128;
  const char* Ab = (const char*)A;
  const char* Bb = (const char*)Bt;
  f4 acc[4][4];
#pragma unroll
  for (int i = 0; i < 4; ++i)
#pragma unroll
    for (int j = 0; j < 4; ++j) acc[i][j] = f4{0.f, 0.f, 0.f, 0.f};

  for (int k0 = 0; k0 < K; k0 += 32) {
#pragma unroll
    for (int p = 0; p < 2; ++p) {
      int off = p * 4096 + tid * 16;
      int r = off >> 6, cb = off & 63;
      int sw = cb ^ ((r & 3) << 4);
      gload_lds16(Ab + ((bm + r) * K + k0) * 2 + sw, As + p * 4096 + wid * 1024);
      gload_lds16(Bb + ((bn + r) * K + k0) * 2 + sw, Bs + p * 4096 + wid * 1024);
    }
    __syncthreads();
    s8 af[4], bfr[4];
#pragma unroll
    for (int mi = 0; mi < 4; ++mi) {
      int r = wy * 64 + mi * 16 + lr;
      int x = r * 64 + lk * 16;
      af[mi] = *(const s8*)(As + (x ^ ((r & 3) << 4)));
    }
#pragma unroll
    for (int ni = 0; ni < 4; ++ni) {
      int r = wx * 64 + ni * 16 + lr;
      int x = r * 64 + lk * 16;
      bfr[ni] = *(const s8*)(Bs + (x ^ ((r & 3) << 4)));
    }
#pragma unroll
    for (int mi = 0; mi < 4; ++mi)
#pragma unroll
      for (int ni = 0; ni < 4; ++ni)
        acc[mi][ni] = __builtin_amdgcn_mfma_f32_16x16x32_bf16(af[mi], bfr[ni], acc[mi][ni], 0, 0, 0);
    __syncthreads();
  }
#pragma unroll
  for (int mi = 0; mi < 4; ++mi)
#pragma unroll
    for (int ni = 0; ni < 4; ++ni)
#pragma unroll
      for (int j = 0; j < 4; ++j) {
        long row = bm + wy * 64 + mi * 16 + lk * 4 + j;
        long col = bn + wx * 64 + ni * 16 + lr;
        float v = acc[mi][ni][j] + bias[col];
        long off;
        if constexpr (REMAP == 1) {
          off = ((row & 63) * 512 + (row >> 6)) * (long)N + col;
        } else if constexpr (REMAP == 2) {
          long tt = row >> 6, b = row & 63;
          long gg = col >> 10, u = col & 1023;
          off = (((((tt << 3) + (b >> 3)) << 5) + (u >> 5)) * 4 + gg) * 256 +
                ((b & 7) << 5) + (u & 31);
        } else {
          off = row * (long)N + col;
        }
        if constexpr (sizeof(OutT) == 2) C[off] = f2bf(v);
        else                              C[off] = v;
      }
}

// ---------------- persistent LSTM recurrence (XCD-local exchange) ----------------
// 256 WGs x 512 threads, 1 WG/CU. WG = (rb = wg&7: 8 batch rows) x (ug = wg>>3: 32 units).
// rb == wg%8 == XCD (assumed round-robin) -> h exchange for a row-group stays in one
// XCD's L2. Correctness does NOT depend on the mapping: producers store plain (local
// L2) + agent-scope (IF$); consumers poll sc0, escalating to sc0+sc1 after 6 tries;
// the tag in each word self-validates whichever cache answers.
// 8 waves = (gate g = wid&3) x (K-half kh = wid>>2). Weights in VGPRs (128/thread).
// LDS swizzle NOTE: rows are 64 B, so the XOR must stay in bits 4-5 (&3, not &7) —
// a 3-bit XOR crosses into the row field and is NOT bijective (the round-6 bug).
__global__ __launch_bounds__(512, 2) void k_lstm_p(
    const short* __restrict__ XG,     // [512][8][32][4][8][32] permuted, bias folded
    const short* __restrict__ Wht,    // [4096][1024]
    unsigned int* __restrict__ hbuf,  // [2][64][1024] tagged: (bf16 h <<16) | (t+1)
    short* __restrict__ HS) {         // [512][64][1024] bf16
  __shared__ __align__(16) char hA[32768];   // [32 kc][16 row][64B], XOR swz bits4-5
  __shared__ float pre[2][4][8][33];          // [kh][gate][row][unit]

  const int tid = threadIdx.x;
  const int wg = blockIdx.x;
  const int wid = tid >> 6, lane = tid & 63;
  const int lr = lane & 15, lk = lane >> 4;
  const int g = wid & 3, kh = wid >> 2;
  const int rb = wg & 7, ug = wg >> 3;

  // recurrent-weight B-fragments: [nt(2)][kc(16)] = 32 x s8 = 128 VGPR
  s8 wf[32];
  {
    const short* wbase = Wht + (long)(g * 1024 + ug * 32 + lr) * 1024 + kh * 512 + lk * 8;
#pragma unroll
    for (int nt = 0; nt < 2; ++nt)
#pragma unroll
      for (int kc = 0; kc < 16; ++kc)
        wf[nt * 16 + kc] = *(const s8*)(wbase + nt * 16384 + kc * 32);
  }
#pragma unroll
  for (int i = 0; i < 32; ++i) asm volatile("" : "+v"(wf[i]));

  const int srow = tid >> 6;              // staging row 0..7 (= wave id)
  // zero pad rows 8..15 of hA once (MFMA M=16, only 8 real rows)
  {
    int zr = 8 + srow;
    int kc = lane >> 1;
    int base = kc * 1024 + zr * 64 + (lane & 1) * 32;
    int sw = ((zr + kc) & 3) << 4;
    *(u4*)(hA + (base ^ sw)) = u4{0, 0, 0, 0};
    *(u4*)(hA + ((base + 16) ^ sw)) = u4{0, 0, 0, 0};
  }

  const int erow = tid >> 5, eu = tid & 31;      // elementwise ids (tid<256)
  const int grow = rb * 8 + (erow & 7);
  const int gu = ug * 32 + eu;
  float c = 0.f;

  // h0 = 0 with tag 1 (parity-0 buffer): plain (L2) + agent (IF$)
  if (tid < 256) {
    unsigned int* p = &hbuf[(long)grow * 1024 + gu];
    *(volatile unsigned int*)p = 1u;
    __hip_atomic_store(p, 1u, __ATOMIC_RELAXED, __HIP_MEMORY_SCOPE_AGENT);
  }

  // XG prefetch for t=0 (elementwise threads only; 4 gate values each)
  short xA0 = 0, xA1 = 0, xA2 = 0, xA3 = 0, xB0, xB1, xB2, xB3;
  if (tid < 256) {
    const short* ep = XG + (long)((0 * 8 + rb) * 32 + ug) * 1024 + erow * 32 + eu;
    xA0 = ep[0]; xA1 = ep[256]; xA2 = ep[512]; xA3 = ep[768];
  }

  for (int t = 0; t < 512; ++t) {
    const unsigned int* cur = hbuf + (t & 1) * 65536;
    unsigned int* nxt = hbuf + ((t + 1) & 1) * 65536;
    const unsigned int tagw = (unsigned int)(t + 1) * 0x10001u;

    // ---- poll-stage h rows [rb*8,+8): 4 x dwordx4 per thread, concurrent retry ----
    const unsigned int* rowp = cur + (long)(rb * 8 + srow) * 1024 + lane * 16;
    u4 v0 = load4_sc0(rowp);
    u4 v1 = load4_sc0(rowp + 4);
    u4 v2 = load4_sc0(rowp + 8);
    u4 v3 = load4_sc0(rowp + 12);
    vm0_fence();
    {
      int tries = 0;
      while (true) {
        int b0 = tagok(v0, tagw), b1 = tagok(v1, tagw);
        int b2 = tagok(v2, tagw), b3 = tagok(v3, tagw);
        if (b0 & b1 & b2 & b3) break;
        if (++tries > (1 << 20)) break;
        if (tries <= 6) {
          if (!b0) v0 = load4_sc0(rowp);
          if (!b1) v1 = load4_sc0(rowp + 4);
          if (!b2) v2 = load4_sc0(rowp + 8);
          if (!b3) v3 = load4_sc0(rowp + 12);
        } else {
          if (!b0) v0 = load4_sc01(rowp);
          if (!b1) v1 = load4_sc01(rowp + 4);
          if (!b2) v2 = load4_sc01(rowp + 8);
          if (!b3) v3 = load4_sc01(rowp + 12);
        }
        vm0_fence();
      }
    }
    // strip tags -> bf16, write swizzled LDS (2 x b128 per thread)
    {
      int kc = lane >> 1;
      int wb = kc * 1024 + srow * 64 + (lane & 1) * 32;
      int sw = ((srow + kc) & 3) << 4;
      u4 hiA, hiB;
      hiA[0] = __builtin_amdgcn_perm(v0[1], v0[0], 0x07060302u);
      hiA[1] = __builtin_amdgcn_perm(v0[3], v0[2], 0x07060302u);
      hiA[2] = __builtin_amdgcn_perm(v1[1], v1[0], 0x07060302u);
      hiA[3] = __builtin_amdgcn_perm(v1[3], v1[2], 0x07060302u);
      hiB[0] = __builtin_amdgcn_perm(v2[1], v2[0], 0x07060302u);
      hiB[1] = __builtin_amdgcn_perm(v2[3], v2[2], 0x07060302u);
      hiB[2] = __builtin_amdgcn_perm(v3[1], v3[0], 0x07060302u);
      hiB[3] = __builtin_amdgcn_perm(v3[3], v3[2], 0x07060302u);
      *(u4*)(hA + (wb ^ sw)) = hiA;
      *(u4*)(hA + ((wb + 16) ^ sw)) = hiB;
    }

    // XG prefetch t+1 (lands under MFMA; consumed next step's elementwise)
    if (tid < 256) {
      const short* ep = XG + (long)((((t + 1) & 511) * 8 + rb) * 32 + ug) * 1024 + erow * 32 + eu;
      xB0 = ep[0]; xB1 = ep[256]; xB2 = ep[512]; xB3 = ep[768];
    }
    __syncthreads();

    // ---- MFMA: 16 A-reads, 32 MFMA per wave (2 independent 16-chains) ----
    f4 a0{0.f, 0.f, 0.f, 0.f}, a1{0.f, 0.f, 0.f, 0.f};
#pragma unroll
    for (int kc2 = 0; kc2 < 16; ++kc2) {
      int kci = kh * 16 + kc2;
      int ad = (kci * 1024 + lr * 64 + lk * 16) ^ (((lr + kci) & 3) << 4);
      s8 ah = *(const s8*)(hA + ad);
      a0 = __builtin_amdgcn_mfma_f32_16x16x32_bf16(ah, wf[kc2], a0, 0, 0, 0);
      a1 = __builtin_amdgcn_mfma_f32_16x16x32_bf16(ah, wf[16 + kc2], a1, 0, 0, 0);
    }

    // ---- gate-partial exchange (C/D: col=lr, row=lk*4+j; keep rows 0-7) ----
    if (lk < 2) {
#pragma unroll
      for (int j = 0; j < 4; ++j) {
        pre[kh][g][lk * 4 + j][lr] = a0[j];
        pre[kh][g][lk * 4 + j][16 + lr] = a1[j];
      }
    }
    __syncthreads();

    // ---- elementwise state update + publish ----
    if (tid < 256) {
      float pi = pre[0][0][erow][eu] + pre[1][0][erow][eu] + bf2f(xA0);
      float pf = pre[0][1][erow][eu] + pre[1][1][erow][eu] + bf2f(xA1);
      float po = pre[0][2][erow][eu] + pre[1][2][erow][eu] + bf2f(xA2);
      float pc = pre[0][3][erow][eu] + pre[1][3][erow][eu] + bf2f(xA3);
      float fi = sigm(pi), ff = sigm(pf), fo = sigm(po);
      float ch = tanhf(pc);
      c = ff * c + fi * ch;
      float h = fo * tanhf(c);
      short hh = f2bf(h);
      unsigned int w = ((unsigned int)(unsigned short)hh << 16) | (unsigned int)(t + 2);
      unsigned int* p = &nxt[(long)grow * 1024 + gu];
      *(volatile unsigned int*)p = w;                                   // local L2
      __hip_atomic_store(p, w, __ATOMIC_RELAXED, __HIP_MEMORY_SCOPE_AGENT);  // IF$
      HS[(long)t * 65536 + (long)grow * 1024 + gu] = hh;
      xA0 = xB0; xA1 = xB1; xA2 = xB2; xA3 = xB3;
    }
  }
}

// ---------------- launch ----------------
extern "C" void kernel_launch(void* const* d_in, const int* in_sizes, int n_in,
                              void* d_out, int out_size, void* d_ws, size_t ws_size,
                              hipStream_t stream) {
  const float* x = (const float*)d_in[0];
  const float* Wx[4] = {(const float*)d_in[1], (const float*)d_in[4], (const float*)d_in[7], (const float*)d_in[10]};
  const float* Wh[4] = {(const float*)d_in[2], (const float*)d_in[5], (const float*)d_in[8], (const float*)d_in[11]};
  const float* bg[4] = {(const float*)d_in[3], (const float*)d_in[6], (const float*)d_in[9], (const float*)d_in[12]};
  const float* Why = (const float*)d_in[13];
  const float* by  = (const float*)d_in[14];

  char* ws = (char*)d_ws;                     // layout (bytes):
  short* xbf  = (short*)(ws);                 // 67,108,864  x bf16 [512][64][1024]
  short* HS   = (short*)(ws);                 // reuses xbf (dead after big GEMM)
  short* Wxt  = (short*)(ws + 67108864);      //  8,388,608
  short* Wht  = (short*)(ws + 75497472);      //  8,388,608
  short* Whyt = (short*)(ws + 83886080);      //  2,097,152
  float* bcat = (float*)(ws + 85983232);      //     16,384
  short* XG   = (short*)(ws + 85999616);      // 268,435,456 [512][8][32][4][8][32]
  unsigned int* hbuf = (unsigned int*)(ws + 354435072);  // 524,288 [2][64][1024]

  hipLaunchKernelGGL(k_x_relayout, dim3(16384), dim3(256), 0, stream, x, xbf);
  for (int gi = 0; gi < 4; ++gi) {
    hipLaunchKernelGGL(k_transpose_c, dim3(32, 32), dim3(256), 0, stream, Wx[gi], Wxt + (long)gi * 1048576);
    hipLaunchKernelGGL(k_transpose_c, dim3(32, 32), dim3(256), 0, stream, Wh[gi], Wht + (long)gi * 1048576);
  }
  hipLaunchKernelGGL(k_transpose_c, dim3(32, 32), dim3(256), 0, stream, Why, Whyt);
  hipLaunchKernelGGL(k_bcat, dim3(16), dim3(256), 0, stream, bg[0], bg[1], bg[2], bg[3], bcat);

  hipLaunchKernelGGL((k_gemm_bt<short, 2>), dim3(32, 256), dim3(256), 0, stream,
                     xbf, Wxt, bcat, XG, 32768, 4096, 1024);

  {
    void* args[] = { (void*)&XG, (void*)&Wht, (void*)&hbuf, (void*)&HS };
    hipLaunchCooperativeKernel((void*)k_lstm_p, dim3(256), dim3(512), args, 0, stream);
  }

  hipLaunchKernelGGL((k_gemm_bt<float, 1>), dim3(8, 256), dim3(256), 0, stream,
                     HS, Whyt, by, (float*)d_out, 32768, 1024, 1024);
}

// Round 8
// 2352.318 us; speedup vs baseline: 2.3865x; 1.5207x over previous
//
#include <hip/hip_runtime.h>
#include <hip/hip_bf16.h>

typedef __attribute__((ext_vector_type(8))) short s8;
typedef __attribute__((ext_vector_type(4))) float f4;
typedef __attribute__((ext_vector_type(4))) unsigned int u4;

#define DEVI static __device__ __forceinline__

DEVI float bf2f(short u) {
  union { float f; unsigned int i; } v;
  v.i = ((unsigned int)(unsigned short)u) << 16;
  return v.f;
}
DEVI short f2bf(float f) {
  union { float f; unsigned int i; } v; v.f = f;
  unsigned int r = v.i + 0x7fffu + ((v.i >> 16) & 1u);
  return (short)(r >> 16);
}
DEVI void gload_lds16(const void* g, void* l) {
  __builtin_amdgcn_global_load_lds(
      (const __attribute__((address_space(1))) unsigned int*)g,
      (__attribute__((address_space(3))) unsigned int*)l, 16, 0, 0);
}
DEVI float sigm(float x) { return 1.f / (1.f + __expf(-x)); }

// sc0: bypass L1, serviced by local (XCD) L2
DEVI u4 load4_sc0(const void* p) {
  u4 v;
  asm volatile("global_load_dwordx4 %0, %1, off sc0" : "=v"(v) : "v"(p) : "memory");
  return v;
}
// sc0 sc1: bypass L1+L2, serviced by IF$ (cross-XCD-safe)
DEVI u4 load4_sc01(const void* p) {
  u4 v;
  asm volatile("global_load_dwordx4 %0, %1, off sc0 sc1" : "=v"(v) : "v"(p) : "memory");
  return v;
}
DEVI unsigned int loadw_sc0(const unsigned int* p) {
  unsigned int v;
  asm volatile("global_load_dword %0, %1, off sc0" : "=v"(v) : "v"(p) : "memory");
  asm volatile("s_waitcnt vmcnt(0)" ::: "memory");
  return v;
}
DEVI unsigned int loadw_sc01(const unsigned int* p) {
  unsigned int v;
  asm volatile("global_load_dword %0, %1, off sc0 sc1" : "=v"(v) : "v"(p) : "memory");
  asm volatile("s_waitcnt vmcnt(0)" ::: "memory");
  return v;
}
DEVI void vm0_fence() {
  asm volatile("s_waitcnt vmcnt(0)" ::: "memory");
  __builtin_amdgcn_sched_barrier(0);
}

// ---------------- converts ----------------
// x [64][512][1024] f32  ->  xbf [512][64][1024] bf16 (t-major rows)
__global__ void k_x_relayout(const float* __restrict__ in, short* __restrict__ out) {
  long idx8 = (long)blockIdx.x * blockDim.x + threadIdx.x;
  long E = idx8 * 8;
  long row = E >> 10;
  long col = E & 1023;
  long t = row >> 6, b = row & 63;
  const float* src = in + ((b << 9) + t) * 1024 + col;
  float4 a = *(const float4*)(src);
  float4 c = *(const float4*)(src + 4);
  s8 o;
  o[0] = f2bf(a.x); o[1] = f2bf(a.y); o[2] = f2bf(a.z); o[3] = f2bf(a.w);
  o[4] = f2bf(c.x); o[5] = f2bf(c.y); o[6] = f2bf(c.z); o[7] = f2bf(c.w);
  *(s8*)(out + E) = o;
}

// src [1024][1024] f32 row-major [k][n]  ->  dst [1024][1024] bf16 at [n][k]
__global__ void k_transpose_c(const float* __restrict__ src, short* __restrict__ dst) {
  __shared__ float tile[32][33];
  int n0 = blockIdx.x * 32, k0 = blockIdx.y * 32;
  int lx = threadIdx.x & 31, ly = threadIdx.x >> 5;
#pragma unroll
  for (int r = 0; r < 32; r += 8)
    tile[ly + r][lx] = src[(long)(k0 + ly + r) * 1024 + n0 + lx];
  __syncthreads();
#pragma unroll
  for (int r = 0; r < 32; r += 8)
    dst[(long)(n0 + ly + r) * 1024 + k0 + lx] = f2bf(tile[lx][ly + r]);
}

__global__ void k_bcat(const float* __restrict__ b0, const float* __restrict__ b1,
                       const float* __restrict__ b2, const float* __restrict__ b3,
                       float* __restrict__ o) {
  int i = blockIdx.x * 256 + threadIdx.x;
  int j = i & 1023;
  float v;
  switch (i >> 10) { case 0: v = b0[j]; break; case 1: v = b1[j]; break;
                     case 2: v = b2[j]; break; default: v = b3[j]; }
  o[i] = v;
}

// ---------------- bf16 GEMM: C[M][N] = A[M][K] @ Bt[N][K]^T + bias ----------------
// REMAP 0: linear. 1: row (t*64+b) -> (b*512+t).
// REMAP 2: XG permute [t][rb8][ug32][g4][row8][u32] for the recurrence kernel.
template <typename OutT, int REMAP>
__global__ __launch_bounds__(256) void k_gemm_bt(
    const short* __restrict__ A, const short* __restrict__ Bt,
    const float* __restrict__ bias, OutT* __restrict__ C,
    int M, int N, int K) {
  __shared__ __align__(16) char As[8192];
  __shared__ __align__(16) char Bs[8192];
  const int tid = threadIdx.x;
  const int wid = tid >> 6, lane = tid & 63;
  const int lr = lane & 15, lk = lane >> 4;
  const int wy = wid >> 1, wx = wid & 1;
  const long bm = (long)blockIdx.y * 128, bn = (long)blockIdx.x * 128;
  const char* Ab = (const char*)A;
  const char* Bb = (const char*)Bt;
  f4 acc[4][4];
#pragma unroll
  for (int i = 0; i < 4; ++i)
#pragma unroll
    for (int j = 0; j < 4; ++j) acc[i][j] = f4{0.f, 0.f, 0.f, 0.f};

  for (int k0 = 0; k0 < K; k0 += 32) {
#pragma unroll
    for (int p = 0; p < 2; ++p) {
      int off = p * 4096 + tid * 16;
      int r = off >> 6, cb = off & 63;
      int sw = cb ^ ((r & 3) << 4);
      gload_lds16(Ab + ((bm + r) * K + k0) * 2 + sw, As + p * 4096 + wid * 1024);
      gload_lds16(Bb + ((bn + r) * K + k0) * 2 + sw, Bs + p * 4096 + wid * 1024);
    }
    __syncthreads();
    s8 af[4], bfr[4];
#pragma unroll
    for (int mi = 0; mi < 4; ++mi) {
      int r = wy * 64 + mi * 16 + lr;
      int x = r * 64 + lk * 16;
      af[mi] = *(const s8*)(As + (x ^ ((r & 3) << 4)));
    }
#pragma unroll
    for (int ni = 0; ni < 4; ++ni) {
      int r = wx * 64 + ni * 16 + lr;
      int x = r * 64 + lk * 16;
      bfr[ni] = *(const s8*)(Bs + (x ^ ((r & 3) << 4)));
    }
#pragma unroll
    for (int mi = 0; mi < 4; ++mi)
#pragma unroll
      for (int ni = 0; ni < 4; ++ni)
        acc[mi][ni] = __builtin_amdgcn_mfma_f32_16x16x32_bf16(af[mi], bfr[ni], acc[mi][ni], 0, 0, 0);
    __syncthreads();
  }
#pragma unroll
  for (int mi = 0; mi < 4; ++mi)
#pragma unroll
    for (int ni = 0; ni < 4; ++ni)
#pragma unroll
      for (int j = 0; j < 4; ++j) {
        long row = bm + wy * 64 + mi * 16 + lk * 4 + j;
        long col = bn + wx * 64 + ni * 16 + lr;
        float v = acc[mi][ni][j] + bias[col];
        long off;
        if constexpr (REMAP == 1) {
          off = ((row & 63) * 512 + (row >> 6)) * (long)N + col;
        } else if constexpr (REMAP == 2) {
          long tt = row >> 6, b = row & 63;
          long gg = col >> 10, u = col & 1023;
          off = (((((tt << 3) + (b >> 3)) << 5) + (u >> 5)) * 4 + gg) * 256 +
                ((b & 7) << 5) + (u & 31);
        } else {
          off = row * (long)N + col;
        }
        if constexpr (sizeof(OutT) == 2) C[off] = f2bf(v);
        else                              C[off] = v;
      }
}

// ---------------- persistent LSTM recurrence (flag-sync, XCD-local fast path) ----
// 256 WGs x 512 threads, 1 WG/CU. WG = (rb = wg&7: 8 batch rows) x (ug = wg>>3: 32 units).
// Sync protocol per step:
//   producer: store h (plain->local L2 AND agent->IF$), vmcnt(0), barrier,
//             tid0 stores flag = t+2 (plain + agent).
//   consumer: wave0's 32 lanes poll the 32 flags of rb (sc0, 128 B/round);
//             sticky escalation to sc0+sc1 if >8 rounds (cross-XCD mapping);
//             then ONE 16 KB bulk load of the h slab (sc0 or sc01 per eflag).
// Release ordering makes data valid behind the flag in both paths; escalation is
// sticky so a broken wg->XCD mapping only costs latency, never correctness.
__global__ __launch_bounds__(512, 2) void k_lstm_p(
    const short* __restrict__ XG,     // [512][8][32][4][8][32] permuted, bias folded
    const short* __restrict__ Wht,    // [4096][1024]
    short* __restrict__ hbuf,         // [2][64][1024] bf16
    unsigned int* __restrict__ flags, // [256] monotonic, spaced 16 u32 (64 B)
    short* __restrict__ HS) {         // [512][64][1024] bf16
  __shared__ __align__(16) char hA[32768];   // [32 kc][16 row][64B], XOR swz bits4-5
  __shared__ float pre[2][4][8][33];          // [kh][gate][row][unit]
  __shared__ int eflag;                       // sticky: 1 => IF$-scope everywhere

  const int tid = threadIdx.x;
  const int wg = blockIdx.x;
  const int wid = tid >> 6, lane = tid & 63;
  const int lr = lane & 15, lk = lane >> 4;
  const int g = wid & 3, kh = wid >> 2;
  const int rb = wg & 7, ug = wg >> 3;

  if (tid == 0) eflag = 0;

  // recurrent-weight B-fragments: [nt(2)][kc(16)] = 32 x s8 (live in AGPR/VGPR file)
  s8 wf[32];
  {
    const short* wbase = Wht + (long)(g * 1024 + ug * 32 + lr) * 1024 + kh * 512 + lk * 8;
#pragma unroll
    for (int nt = 0; nt < 2; ++nt)
#pragma unroll
      for (int kc = 0; kc < 16; ++kc)
        wf[nt * 16 + kc] = *(const s8*)(wbase + nt * 16384 + kc * 32);
  }
#pragma unroll
  for (int i = 0; i < 32; ++i) asm volatile("" : "+v"(wf[i]));

  const int srow = tid >> 6;              // staging row 0..7 (= wave id)
  // zero pad rows 8..15 of hA once (MFMA M=16, only 8 real rows)
  {
    int zr = 8 + srow;
    int kc = lane >> 1;
    int base = kc * 1024 + zr * 64 + (lane & 1) * 32;
    int sw = ((zr + kc) & 3) << 4;
    *(u4*)(hA + (base ^ sw)) = u4{0, 0, 0, 0};
    *(u4*)(hA + ((base + 16) ^ sw)) = u4{0, 0, 0, 0};
  }

  const int erow = tid >> 5, eu = tid & 31;      // elementwise ids (tid<256)
  const int grow = rb * 8 + (erow & 7);
  const int gu = ug * 32 + eu;
  float c = 0.f;

  // h0 = 0 (parity-0) + publish flag=1
  if (tid < 256) {
    short* p = &hbuf[(long)grow * 1024 + gu];
    *(volatile short*)p = 0;
    __hip_atomic_store(p, (short)0, __ATOMIC_RELAXED, __HIP_MEMORY_SCOPE_AGENT);
  }
  vm0_fence();
  __syncthreads();
  if (tid == 0) {
    unsigned int* f = &flags[(unsigned)((rb << 5) + ug) << 4];
    *(volatile unsigned int*)f = 1u;
    __hip_atomic_store(f, 1u, __ATOMIC_RELAXED, __HIP_MEMORY_SCOPE_AGENT);
  }

  // XG prefetch for t=0 (elementwise threads only; 4 gate values each)
  short xA0 = 0, xA1 = 0, xA2 = 0, xA3 = 0, xB0, xB1, xB2, xB3;
  if (tid < 256) {
    const short* ep = XG + (long)((0 * 8 + rb) * 32 + ug) * 1024 + erow * 32 + eu;
    xA0 = ep[0]; xA1 = ep[256]; xA2 = ep[512]; xA3 = ep[768];
  }

  for (int t = 0; t < 512; ++t) {
    // ---- S0: flag poll (wave 0, lanes 0..31; 128 B per round) ----
    if (wid == 0 && lane < 32) {
      const unsigned int* f = &flags[(unsigned)((rb << 5) + lane) << 4];
      const unsigned int target = (unsigned int)(t + 1);
      int esc = eflag;
      int tries = 0;
      while (true) {
        unsigned int v = esc ? loadw_sc01(f) : loadw_sc0(f);
        if (v >= target) break;
        ++tries;
        if (tries == 8 && !esc) { esc = 1; eflag = 1; }
        if (tries > 64) __builtin_amdgcn_s_sleep(2);
        if (tries > (1 << 20)) break;
      }
    }
    __syncthreads();  // S1: flags confirmed; eflag visible to all waves
    const int esc = eflag;

    // ---- bulk-stage h rows [rb*8,+8): 2 x dwordx4 per thread, ONCE ----
    {
      const char* rowp = (const char*)(hbuf + (t & 1) * 65536 +
                                       (long)(rb * 8 + srow) * 1024) + lane * 32;
      u4 v0, v1;
      if (esc) { v0 = load4_sc01(rowp); v1 = load4_sc01(rowp + 16); }
      else     { v0 = load4_sc0(rowp);  v1 = load4_sc0(rowp + 16); }
      // XG prefetch t+1 (overlaps with the h latency; consumed next elementwise)
      if (tid < 256) {
        const short* ep = XG + (long)((((t + 1) & 511) * 8 + rb) * 32 + ug) * 1024 + erow * 32 + eu;
        xB0 = ep[0]; xB1 = ep[256]; xB2 = ep[512]; xB3 = ep[768];
      }
      vm0_fence();
      int kc = lane >> 1;
      int wb = kc * 1024 + srow * 64 + (lane & 1) * 32;
      int sw = ((srow + kc) & 3) << 4;
      *(u4*)(hA + (wb ^ sw)) = v0;
      *(u4*)(hA + ((wb + 16) ^ sw)) = v1;
    }
    __syncthreads();  // S2: hA ready

    // ---- MFMA: 16 A-reads, 32 MFMA per wave (2 independent 16-chains) ----
    f4 a0{0.f, 0.f, 0.f, 0.f}, a1{0.f, 0.f, 0.f, 0.f};
#pragma unroll
    for (int kc2 = 0; kc2 < 16; ++kc2) {
      int kci = kh * 16 + kc2;
      int ad = (kci * 1024 + lr * 64 + lk * 16) ^ (((lr + kci) & 3) << 4);
      s8 ah = *(const s8*)(hA + ad);
      a0 = __builtin_amdgcn_mfma_f32_16x16x32_bf16(ah, wf[kc2], a0, 0, 0, 0);
      a1 = __builtin_amdgcn_mfma_f32_16x16x32_bf16(ah, wf[16 + kc2], a1, 0, 0, 0);
    }

    // ---- gate-partial exchange (C/D: col=lr, row=lk*4+j; keep rows 0-7) ----
    if (lk < 2) {
#pragma unroll
      for (int j = 0; j < 4; ++j) {
        pre[kh][g][lk * 4 + j][lr] = a0[j];
        pre[kh][g][lk * 4 + j][16 + lr] = a1[j];
      }
    }
    __syncthreads();  // S3: pre ready

    // ---- elementwise state update + h publish ----
    if (tid < 256) {
      float pi = pre[0][0][erow][eu] + pre[1][0][erow][eu] + bf2f(xA0);
      float pf = pre[0][1][erow][eu] + pre[1][1][erow][eu] + bf2f(xA1);
      float po = pre[0][2][erow][eu] + pre[1][2][erow][eu] + bf2f(xA2);
      float pc = pre[0][3][erow][eu] + pre[1][3][erow][eu] + bf2f(xA3);
      float fi = sigm(pi), ff = sigm(pf), fo = sigm(po);
      float ch = tanhf(pc);
      c = ff * c + fi * ch;
      float h = fo * tanhf(c);
      short hh = f2bf(h);
      short* p = &hbuf[((t + 1) & 1) * 65536 + (long)grow * 1024 + gu];
      *(volatile short*)p = hh;                                          // local L2
      __hip_atomic_store(p, hh, __ATOMIC_RELAXED, __HIP_MEMORY_SCOPE_AGENT);  // IF$
      HS[(long)t * 65536 + (long)grow * 1024 + gu] = hh;
      xA0 = xB0; xA1 = xB1; xA2 = xB2; xA3 = xB3;
    }
    vm0_fence();       // all h stores drained (release)
    __syncthreads();   // S4: whole WG's publish complete
    if (tid == 0) {
      unsigned int* f = &flags[(unsigned)((rb << 5) + ug) << 4];
      unsigned int fv = (unsigned int)(t + 2);
      *(volatile unsigned int*)f = fv;                                   // local L2
      __hip_atomic_store(f, fv, __ATOMIC_RELAXED, __HIP_MEMORY_SCOPE_AGENT);  // IF$
    }
  }
}

// ---------------- launch ----------------
extern "C" void kernel_launch(void* const* d_in, const int* in_sizes, int n_in,
                              void* d_out, int out_size, void* d_ws, size_t ws_size,
                              hipStream_t stream) {
  const float* x = (const float*)d_in[0];
  const float* Wx[4] = {(const float*)d_in[1], (const float*)d_in[4], (const float*)d_in[7], (const float*)d_in[10]};
  const float* Wh[4] = {(const float*)d_in[2], (const float*)d_in[5], (const float*)d_in[8], (const float*)d_in[11]};
  const float* bg[4] = {(const float*)d_in[3], (const float*)d_in[6], (const float*)d_in[9], (const float*)d_in[12]};
  const float* Why = (const float*)d_in[13];
  const float* by  = (const float*)d_in[14];

  char* ws = (char*)d_ws;                     // layout (bytes):
  short* xbf  = (short*)(ws);                 // 67,108,864  x bf16 [512][64][1024]
  short* HS   = (short*)(ws);                 // reuses xbf (dead after big GEMM)
  short* Wxt  = (short*)(ws + 67108864);      //  8,388,608
  short* Wht  = (short*)(ws + 75497472);      //  8,388,608
  short* Whyt = (short*)(ws + 83886080);      //  2,097,152
  float* bcat = (float*)(ws + 85983232);      //     16,384
  short* XG   = (short*)(ws + 85999616);      // 268,435,456 [512][8][32][4][8][32]
  short* hbuf = (short*)(ws + 354435072);     //    262,144  [2][64][1024] bf16
  unsigned int* flags = (unsigned int*)(ws + 354697216);  // 16,384

  hipLaunchKernelGGL(k_x_relayout, dim3(16384), dim3(256), 0, stream, x, xbf);
  for (int gi = 0; gi < 4; ++gi) {
    hipLaunchKernelGGL(k_transpose_c, dim3(32, 32), dim3(256), 0, stream, Wx[gi], Wxt + (long)gi * 1048576);
    hipLaunchKernelGGL(k_transpose_c, dim3(32, 32), dim3(256), 0, stream, Wh[gi], Wht + (long)gi * 1048576);
  }
  hipLaunchKernelGGL(k_transpose_c, dim3(32, 32), dim3(256), 0, stream, Why, Whyt);
  hipLaunchKernelGGL(k_bcat, dim3(16), dim3(256), 0, stream, bg[0], bg[1], bg[2], bg[3], bcat);

  hipLaunchKernelGGL((k_gemm_bt<short, 2>), dim3(32, 256), dim3(256), 0, stream,
                     xbf, Wxt, bcat, XG, 32768, 4096, 1024);

  hipMemsetAsync(flags, 0, 16384, stream);

  {
    void* args[] = { (void*)&XG, (void*)&Wht, (void*)&hbuf, (void*)&flags, (void*)&HS };
    hipLaunchCooperativeKernel((void*)k_lstm_p, dim3(256), dim3(512), args, 0, stream);
  }

  hipLaunchKernelGGL((k_gemm_bt<float, 1>), dim3(8, 256), dim3(256), 0, stream,
                     HS, Whyt, by, (float*)d_out, 32768, 1024, 1024);
}